// Round 3
// baseline (293.570 us; speedup 1.0000x reference)
//
#include <hip/hip_runtime.h>
#include <math.h>

typedef _Float16 f16;
typedef f16 f16x8 __attribute__((ext_vector_type(8)));
typedef f16 f16x2 __attribute__((ext_vector_type(2)));
typedef float f32x4 __attribute__((ext_vector_type(4)));

#define NTHREADS 256

constexpr int H = 512, W = 512;
constexpr int TX = 64, TY = 16;        // output tile per block
constexpr int NPLANES = 96;            // 32 * 3
constexpr int GX = W / TX;             // 8
constexpr int GY = H / TY;             // 32
constexpr int NB = GX * GY * NPLANES;  // 24576 blocks
constexpr double NTOT = 25165824.0;    // 32*3*512*512
constexpr float C1 = 1.0e-4f;
constexpr float C2 = 9.0e-4f;

// LDS geometry. preS: [ch][halo col][halo row], column-major per channel so the
// stage-V B-fragment (8 consecutive input ROWS per lane) is one ds_read_b128.
// Col pitch 40 f16 = 80 B = 20 words mod 32 banks -> 8 distinct start banks,
// 2-way (free). vcS row pitch 88 f16 = 176 B = 44 words -> same property.
constexpr int PRE_COLS = 80;   // 74 used + pad (pad cols zero-filled)
constexpr int PRE_RP   = 40;   // rows: 26 used + pad (zero-filled to 32)
constexpr int VC_P     = 88;

struct Wts { float w[11]; };

__device__ __forceinline__ void store_pre(f16 (&preS)[4][PRE_COLS][PRE_RP],
                                          int c, int rp,
                                          float v1a, float v1b, float v2a, float v2b)
{
    const float A0 = v1a + v2a, B0 = v1a - v2a;
    const float A1 = v1b + v2b, B1 = v1b - v2b;
    f16x2 hA  = { (f16)A0,        (f16)A1 };
    f16x2 hB  = { (f16)B0,        (f16)B1 };
    f16x2 hQa = { (f16)(A0 * A0), (f16)(A1 * A1) };
    f16x2 hQb = { (f16)(B0 * B0), (f16)(B1 * B1) };
    *(f16x2*)&preS[0][c][2 * rp] = hA;
    *(f16x2*)&preS[1][c][2 * rp] = hB;
    *(f16x2*)&preS[2][c][2 * rp] = hQa;
    *(f16x2*)&preS[3][c][2 * rp] = hQb;
}

__global__ __launch_bounds__(NTHREADS, 4)
void ssim_main(const float* __restrict__ img1, const float* __restrict__ img2,
               float* __restrict__ part, Wts wts)
{
    __shared__ __align__(16) f16 preS[4][PRE_COLS][PRE_RP];  // 25600 B
    __shared__ __align__(16) f16 vcS[4][16][VC_P];           // 11264 B
    __shared__ __align__(16) f16 TbS[16][40];                //  1280 B
    __shared__ float red[4];

    const int tid = threadIdx.x;
    const int tx0 = blockIdx.x * TX;
    const int ty0 = blockIdx.y * TY;
    const size_t plane = (size_t)blockIdx.z * (size_t)(H * W);
    const float* p1 = img1 + plane;
    const float* p2 = img2 + plane;

    // Toeplitz T[m][k] = w[k-m] (zero outside the 11-tap band). Shared by both
    // conv stages as the MFMA A-operand. k>=26 rows of the zero band multiply
    // the LDS pad regions -> pads only need to be finite, but we zero them
    // anyway (stale LDS could hold NaN, and NaN*0 = NaN).
    for (int i = tid; i < 512; i += NTHREADS) {
        const int m = i >> 5, k = i & 31, d = k - m;
        TbS[m][k] = (d >= 0 && d <= 10) ? (f16)wts.w[d] : (f16)0.0f;
    }

    const bool edge = (blockIdx.x == 0) || (blockIdx.x == GX - 1) ||
                      (blockIdx.y == 0) || (blockIdx.y == GY - 1);

    // Phase 0: global -> preS {a, b, a^2, b^2} in f16, column-major, row pairs.
    // 80 cols x 16 row-pairs = 1280 items = exactly 5 iterations of 256.
    if (!edge) {
        #pragma unroll
        for (int t = 0; t < 5; ++t) {
            const int i  = t * NTHREADS + tid;
            const int c  = i % PRE_COLS;
            const int rp = i / PRE_COLS;          // 0..15
            const bool valid = (c < 74) & (rp < 13);
            const int x = tx0 - 5 + c;
            const int y = ty0 - 5 + 2 * rp;
            float v1a = 0.f, v1b = 0.f, v2a = 0.f, v2b = 0.f;
            if (valid) {
                const float* q1 = p1 + y * W + x;
                const float* q2 = p2 + y * W + x;
                v1a = q1[0]; v1b = q1[W];
                v2a = q2[0]; v2b = q2[W];
            }
            store_pre(preS, c, rp, v1a, v1b, v2a, v2b);
        }
    } else {
        #pragma unroll
        for (int t = 0; t < 5; ++t) {
            const int i  = t * NTHREADS + tid;
            const int c  = i % PRE_COLS;
            const int rp = i / PRE_COLS;
            const int x = tx0 - 5 + c;
            const int y = ty0 - 5 + 2 * rp;
            const bool cv = (c < 74) && (rp < 13) && (x >= 0) && (x < W);
            float v1a = 0.f, v1b = 0.f, v2a = 0.f, v2b = 0.f;
            if (cv && y >= 0 && y < H)         { v1a = p1[y * W + x];       v2a = p2[y * W + x]; }
            if (cv && y + 1 >= 0 && y + 1 < H) { v1b = p1[(y + 1) * W + x]; v2b = p2[(y + 1) * W + x]; }
            store_pre(preS, c, rp, v1a, v1b, v2a, v2b);
        }
    }
    __syncthreads();

    const int lane = tid & 63;
    const int wave = tid >> 6;
    const int tr = lane & 15;           // A row / B col / C col index
    const int k0 = (lane >> 4) * 8;     // K base for A/B fragments
    const int m0 = (lane >> 4) * 4;     // C/D row base

    const f16x8 aT = *(const f16x8*)&TbS[tr][k0];
    const f32x4 zero4 = { 0.f, 0.f, 0.f, 0.f };

    // Stage V (vertical conv): wave = channel; 5 col-groups of 16.
    // C[m][n] = sum_k w[k-m] * pre[col0+n][row k]  -> vconv row m, col col0+n.
    {
        const int ch = wave;
        #pragma unroll
        for (int cg = 0; cg < 5; ++cg) {
            const f16x8 bf = *(const f16x8*)&preS[ch][cg * 16 + tr][k0];
            const f32x4 d = __builtin_amdgcn_mfma_f32_16x16x32_f16(aT, bf, zero4, 0, 0, 0);
            const int col = cg * 16 + tr;
            #pragma unroll
            for (int i2 = 0; i2 < 4; ++i2)
                vcS[ch][m0 + i2][col] = (f16)d[i2];
        }
    }
    __syncthreads();

    // Stage H (horizontal conv): wave = output col-group; all 4 channels land
    // on the same lane for the same pixel. C[m][n] = out[row n][col 16G+m].
    f32x4 r0, r1, r2, r3;
    {
        const int G = wave;
        r0 = __builtin_amdgcn_mfma_f32_16x16x32_f16(aT, *(const f16x8*)&vcS[0][tr][G * 16 + k0], zero4, 0, 0, 0);
        r1 = __builtin_amdgcn_mfma_f32_16x16x32_f16(aT, *(const f16x8*)&vcS[1][tr][G * 16 + k0], zero4, 0, 0, 0);
        r2 = __builtin_amdgcn_mfma_f32_16x16x32_f16(aT, *(const f16x8*)&vcS[2][tr][G * 16 + k0], zero4, 0, 0, 0);
        r3 = __builtin_amdgcn_mfma_f32_16x16x32_f16(aT, *(const f16x8*)&vcS[3][tr][G * 16 + k0], zero4, 0, 0, 0);
    }

    // SSIM map on registers. A=conv(x1+x2), B=conv(x1-x2), Qa=conv(a^2), Qb=conv(b^2).
    float local = 0.f;
    #pragma unroll
    for (int i2 = 0; i2 < 4; ++i2) {
        const float A  = r0[i2], Bv = r1[i2];
        const float Qa = r2[i2], Qb = r3[i2];
        const float u = A * A, v = Bv * Bv;
        const float t1 = u - v;                              // 4*mu1*mu2
        const float t2 = u + v;                              // 2*(mu1^2+mu2^2)
        const float num1 = fmaf(0.5f, t1, C1);
        const float den1 = fmaf(0.5f, t2, C1);
        const float num2 = fmaf(0.5f, (Qa - Qb) - t1, C2);   // 2*sigma12 + C2
        const float den2 = fmaf(0.5f, (Qa + Qb) - t2, C2);   // sig1+sig2 + C2
        local += (num1 * num2) * __builtin_amdgcn_rcpf(den1 * den2);
    }

    #pragma unroll
    for (int off = 32; off > 0; off >>= 1) local += __shfl_down(local, off, 64);
    if (lane == 0) red[wave] = local;
    __syncthreads();
    if (tid == 0) {
        const float s = red[0] + red[1] + red[2] + red[3];
        const int bid = (blockIdx.z * GY + blockIdx.y) * GX + blockIdx.x;
        part[bid] = s;
    }
}

__global__ __launch_bounds__(1024)
void ssim_final(const float* __restrict__ part, float* __restrict__ out)
{
    __shared__ double red[16];
    const int tid = threadIdx.x;
    double s = 0.0;
    for (int i = tid; i < NB; i += 1024) s += (double)part[i];
    #pragma unroll
    for (int off = 32; off > 0; off >>= 1) s += __shfl_down(s, off, 64);
    if ((tid & 63) == 0) red[tid >> 6] = s;
    __syncthreads();
    if (tid == 0) {
        double t = 0.0;
        #pragma unroll
        for (int w = 0; w < 16; ++w) t += red[w];
        out[0] = (float)(1.0 - t / NTOT);
    }
}

extern "C" void kernel_launch(void* const* d_in, const int* in_sizes, int n_in,
                              void* d_out, int out_size, void* d_ws, size_t ws_size,
                              hipStream_t stream)
{
    const float* img1 = (const float*)d_in[0];
    const float* img2 = (const float*)d_in[1];
    float* out = (float*)d_out;
    float* part = (float*)d_ws;   // NB floats, fully rewritten each call

    Wts wts;
    double wd[11], s = 0.0;
    for (int k = 0; k < 11; ++k) {
        const double d = (double)(k - 5);
        wd[k] = exp(-0.5 / (1.5 * 1.5) * d * d);
        s += wd[k];
    }
    for (int k = 0; k < 11; ++k) wts.w[k] = (float)(wd[k] / s);

    dim3 grid(GX, GY, NPLANES);
    ssim_main<<<grid, NTHREADS, 0, stream>>>(img1, img2, part, wts);
    ssim_final<<<1, 1024, 0, stream>>>(part, out);
}

// Round 4
// 242.518 us; speedup vs baseline: 1.2105x; 1.2105x over previous
//
#include <hip/hip_runtime.h>
#include <math.h>

typedef float float2v __attribute__((ext_vector_type(2)));
typedef unsigned int u32;
typedef u32 u32x4 __attribute__((ext_vector_type(4)));
typedef _Float16 f16;
typedef f16 f16x2 __attribute__((ext_vector_type(2)));

#define NTHREADS 512

constexpr int H = 512, W = 512;
constexpr int TY = 16;
constexpr int NBANDS = H / TY;          // 32
constexpr int NPLANES = 96;             // 32 batch * 3 ch
constexpr int NB = NBANDS * NPLANES;    // 3072 blocks
constexpr int PITCH = 524;              // u32 row pitch; 524 % 8 == 4 -> b128 reads spread all 8 bank-groups
constexpr int PAIR = 16 * PITCH;        // offset of (Qa,Qb) plane
constexpr double NTOT = 25165824.0;     // 32*3*512*512
constexpr float C1 = 1.0e-4f;
constexpr float C2 = 9.0e-4f;

struct Wts { float w[11]; };

__device__ __forceinline__ float2v up2(u32 w) {
    const f16x2 h = __builtin_bit_cast(f16x2, w);
    return (float2v){(float)h.x, (float)h.y};
}

// Phase 1: one halo column per thread. Vertical 11-tap conv of the channel
// pairs (a,b)=(x1+x2,x1-x2) and (a^2,b^2) via float2 (v_pk_fma_f32), sliding
// register window over 26 rows -> 16 outputs, packed to f16x2, one u32 LDS
// store per pair. Stores are lane-consecutive -> conflict-free.
template<bool EDGE>
__device__ __forceinline__ void do_column(const float* __restrict__ p1,
                                          const float* __restrict__ p2,
                                          u32* __restrict__ vc,
                                          const Wts& wts, int cc, int y0)
{
    const int x = cc - 5;
    const bool xok = (x >= 0) && (x < W);
    float2v ab[26], qq[26];
    #pragma unroll
    for (int t = 0; t < 26; ++t) {
        const int y = y0 - 5 + t;
        bool ok = xok;
        if (EDGE) ok = ok && (y >= 0) && (y < H);
        const float v1 = ok ? p1[y * W + x] : 0.f;   // masked load, no OOB access
        const float v2 = ok ? p2[y * W + x] : 0.f;
        ab[t] = (float2v){v1 + v2, v1 - v2};
        qq[t] = ab[t] * ab[t];
    }
    u32* wp = vc + cc;
    #pragma unroll
    for (int r = 0; r < 16; ++r) {
        float2v sP = ab[r] * wts.w[0];
        float2v sQ = qq[r] * wts.w[0];
        #pragma unroll
        for (int k = 1; k < 11; ++k) {
            sP += ab[r + k] * wts.w[k];
            sQ += qq[r + k] * wts.w[k];
        }
        wp[r * PITCH]        = __builtin_bit_cast(u32, __builtin_amdgcn_cvt_pkrtz(sP.x, sP.y));
        wp[r * PITCH + PAIR] = __builtin_bit_cast(u32, __builtin_amdgcn_cvt_pkrtz(sQ.x, sQ.y));
    }
}

__global__ __launch_bounds__(NTHREADS, 4)
void ssim_main(const float* __restrict__ img1, const float* __restrict__ img2,
               float* __restrict__ part, Wts wts)
{
    __shared__ __align__(16) u32 vc[2 * 16 * PITCH];   // 67,072 B -> 2 blocks/CU
    __shared__ float red[8];

    const int tid  = threadIdx.x;
    const int band = blockIdx.x;
    const int y0   = band * TY;
    const size_t plane = (size_t)blockIdx.y * (size_t)(H * W);
    const float* p1 = img1 + plane;
    const float* p2 = img2 + plane;

    // 522 halo columns: thread t does column t; threads 0..9 (all wave 0,
    // lanes run in parallel) take columns 512..521.
    if (band == 0 || band == NBANDS - 1) {
        do_column<true>(p1, p2, vc, wts, tid, y0);
        if (tid < 10) do_column<true>(p1, p2, vc, wts, 512 + tid, y0);
    } else {
        do_column<false>(p1, p2, vc, wts, tid, y0);
        if (tid < 10) do_column<false>(p1, p2, vc, wts, 512 + tid, y0);
    }
    __syncthreads();

    // Phase 2: horizontal 11-tap conv + SSIM map. Thread (r=t&15, G=t>>4)
    // -> row r, cols 16G..16G+15. lane stride PITCH (=4 mod 8 groups) ->
    // b128 reads hit all 8 bank-groups evenly: minimum-cycle, conflict-free.
    const int r = tid & 15;
    const int G = tid >> 4;
    const u32* row0 = vc + r * PITCH + 16 * G;

    float2v AB[26];
    #pragma unroll
    for (int i = 0; i < 7; ++i) {
        const u32x4 t4 = ((const u32x4*)row0)[i];
        #pragma unroll
        for (int e = 0; e < 4; ++e) {
            const int idx = 4 * i + e;
            if (idx < 26) AB[idx] = up2(t4[e]);
        }
    }
    float2v P[16];
    #pragma unroll
    for (int j = 0; j < 16; ++j) {
        float2v s = AB[j] * wts.w[0];
        #pragma unroll
        for (int k = 1; k < 11; ++k) s += AB[j + k] * wts.w[k];
        P[j] = s;
    }

    const u32* row1 = row0 + PAIR;
    float2v QQ[26];
    #pragma unroll
    for (int i = 0; i < 7; ++i) {
        const u32x4 t4 = ((const u32x4*)row1)[i];
        #pragma unroll
        for (int e = 0; e < 4; ++e) {
            const int idx = 4 * i + e;
            if (idx < 26) QQ[idx] = up2(t4[e]);
        }
    }

    float local = 0.f;
    #pragma unroll
    for (int j = 0; j < 16; ++j) {
        float2v sq = QQ[j] * wts.w[0];
        #pragma unroll
        for (int k = 1; k < 11; ++k) sq += QQ[j + k] * wts.w[k];
        const float A  = P[j].x, B = P[j].y;
        const float Qa = sq.x,  Qb = sq.y;
        const float u = A * A, v = B * B;
        const float t1 = u - v;                              // 4*mu1*mu2
        const float t2 = u + v;                              // 2*(mu1^2+mu2^2)
        const float num1 = fmaf(0.5f, t1, C1);
        const float den1 = fmaf(0.5f, t2, C1);
        const float num2 = fmaf(0.5f, (Qa - Qb) - t1, C2);   // 2*sigma12 + C2
        const float den2 = fmaf(0.5f, (Qa + Qb) - t2, C2);   // sig1+sig2 + C2
        local += (num1 * num2) * __builtin_amdgcn_rcpf(den1 * den2);
    }

    #pragma unroll
    for (int off = 32; off > 0; off >>= 1) local += __shfl_down(local, off, 64);
    if ((tid & 63) == 0) red[tid >> 6] = local;
    __syncthreads();
    if (tid == 0) {
        float s = 0.f;
        #pragma unroll
        for (int wv = 0; wv < 8; ++wv) s += red[wv];
        part[blockIdx.y * NBANDS + band] = s;
    }
}

__global__ __launch_bounds__(512)
void ssim_final(const float* __restrict__ part, float* __restrict__ out)
{
    __shared__ double red[8];
    const int tid = threadIdx.x;
    double s = 0.0;
    for (int i = tid; i < NB; i += 512) s += (double)part[i];
    #pragma unroll
    for (int off = 32; off > 0; off >>= 1) s += __shfl_down(s, off, 64);
    if ((tid & 63) == 0) red[tid >> 6] = s;
    __syncthreads();
    if (tid == 0) {
        double t = 0.0;
        #pragma unroll
        for (int wv = 0; wv < 8; ++wv) t += red[wv];
        out[0] = (float)(1.0 - t / NTOT);
    }
}

extern "C" void kernel_launch(void* const* d_in, const int* in_sizes, int n_in,
                              void* d_out, int out_size, void* d_ws, size_t ws_size,
                              hipStream_t stream)
{
    const float* img1 = (const float*)d_in[0];
    const float* img2 = (const float*)d_in[1];
    float* out = (float*)d_out;
    float* part = (float*)d_ws;   // NB floats, fully rewritten each call

    Wts wts;
    double wd[11], s = 0.0;
    for (int k = 0; k < 11; ++k) {
        const double d = (double)(k - 5);
        wd[k] = exp(-0.5 / (1.5 * 1.5) * d * d);
        s += wd[k];
    }
    for (int k = 0; k < 11; ++k) wts.w[k] = (float)(wd[k] / s);

    dim3 grid(NBANDS, NPLANES);
    ssim_main<<<grid, NTHREADS, 0, stream>>>(img1, img2, part, wts);
    ssim_final<<<1, 512, 0, stream>>>(part, out);
}

// Round 5
// 227.129 us; speedup vs baseline: 1.2925x; 1.0678x over previous
//
#include <hip/hip_runtime.h>
#include <math.h>

typedef _Float16 f16;
typedef f16 f16x8 __attribute__((ext_vector_type(8)));
typedef f16 f16x2 __attribute__((ext_vector_type(2)));
typedef float f32x4 __attribute__((ext_vector_type(4)));
typedef unsigned int u32;
typedef u32 u32x2 __attribute__((ext_vector_type(2)));

constexpr int H = 512, W = 512;
constexpr int TY = 16;
constexpr int NBANDS = H / TY;          // 32
constexpr int NPLANES = 96;             // 32 batch * 3 ch
constexpr int NB = NBANDS * NPLANES;    // 3072 blocks
constexpr int VP = 552;                 // vc row pitch (f16): 1104 B = 276 words == 20 mod 32 -> 8-bank spread, 16B-aligned rows
constexpr double NTOT = 25165824.0;     // 32*3*512*512
constexpr float C1 = 1.0e-4f;
constexpr float C2 = 9.0e-4f;

struct Wts { float w[11]; };

__device__ __forceinline__ u32 pk(float lo, float hi) {
    return __builtin_bit_cast(u32, __builtin_amdgcn_cvt_pkrtz(lo, hi));
}

__global__ __launch_bounds__(512, 4)
void ssim_main(const float* __restrict__ img1, const float* __restrict__ img2,
               float* __restrict__ part, Wts wts)
{
    // vconv planes {A=conv(x1+x2), B=conv(x1-x2), Qa=conv(a^2), Qb=conv(b^2)}
    __shared__ __align__(16) f16 vc[4][TY][VP];   // 70,656 B -> 2 blocks/CU
    __shared__ __align__(16) f16 Tb[16][40];      // Toeplitz fragment table
    __shared__ float red[8];

    const int tid  = threadIdx.x;
    const int lane = tid & 63;
    const int wave = tid >> 6;
    const int tr   = lane & 15;          // A-row / B-col index
    const int g    = lane >> 4;          // k-group
    const int k0   = g * 8;

    // Toeplitz T[idx][k] = w[k-idx], zero outside the 11-tap band. The zero
    // band (k>=26 for all idx<=15) multiplies garbage/pad -> contributes 0.
    for (int i = tid; i < 640; i += 512) {
        const int m = i / 40, k = i - m * 40, d = k - m;
        Tb[m][k] = (d >= 0 && d <= 10) ? (f16)wts.w[d] : (f16)0.0f;
    }
    __syncthreads();
    // tw = T[tr][k0..k0+7]; A-layout (row=lane&15,k=k0+j) and B-layout
    // (col=lane&15,k=k0+j) index identically -> same registers serve both.
    const f16x8 tw = *(const f16x8*)&Tb[tr][k0];

    const int band = blockIdx.x;
    const int y0   = band * TY;
    const size_t plane = (size_t)blockIdx.y * (size_t)(H * W);
    const float* p1 = img1 + plane;
    const float* p2 = img2 + plane;

    // Per-lane input rows y = y0-5+k0+j (fixed across tiles): clamp + mask.
    int   rowbase[8];
    float ymul[8];
    #pragma unroll
    for (int j = 0; j < 8; ++j) {
        const int y = y0 - 5 + k0 + j;
        const bool yok = (unsigned)y < (unsigned)H;
        rowbase[j] = (yok ? y : 0) * W;
        ymul[j] = yok ? 1.f : 0.f;
    }

    const f32x4 z4 = { 0.f, 0.f, 0.f, 0.f };

    // ---- Stage V: vertical conv via mfma(A=data, B=Toeplitz). ----
    // D[m][n] = sum_k pre[row y0-5+k][col 16t+m] * w[k-n]
    //         = vconv[row y0+n][halo col 16t+m].
    // Lane(tr,g) reg i -> row tr, cols 16t+4g+i: 4 contiguous f16 = 1 b64 write.
    for (int t = wave; t < 33; t += 8) {
        const int x   = 16 * t + tr - 5;          // image col of halo col 16t+tr
        const bool xok = (unsigned)x < (unsigned)W;
        const int xc  = xok ? x : 0;
        const float xm = xok ? 1.f : 0.f;

        f16x8 fA, fB, fQa, fQb;
        #pragma unroll
        for (int j = 0; j < 8; ++j) {
            const float m  = xm * ymul[j];        // zero-pad mask
            const float a1 = p1[rowbase[j] + xc] * m;
            const float a2 = p2[rowbase[j] + xc] * m;
            const float a = a1 + a2, b = a1 - a2;
            fA[j]  = (f16)a;        fB[j]  = (f16)b;
            fQa[j] = (f16)(a * a);  fQb[j] = (f16)(b * b);
        }
        const f32x4 dA  = __builtin_amdgcn_mfma_f32_16x16x32_f16(fA,  tw, z4, 0, 0, 0);
        const f32x4 dB  = __builtin_amdgcn_mfma_f32_16x16x32_f16(fB,  tw, z4, 0, 0, 0);
        const f32x4 dQa = __builtin_amdgcn_mfma_f32_16x16x32_f16(fQa, tw, z4, 0, 0, 0);
        const f32x4 dQb = __builtin_amdgcn_mfma_f32_16x16x32_f16(fQb, tw, z4, 0, 0, 0);

        const int cb = 16 * t + 4 * g;            // 8B-aligned f16 offset
        { u32x2 v = { pk(dA[0],  dA[1]),  pk(dA[2],  dA[3])  }; *(u32x2*)&vc[0][tr][cb] = v; }
        { u32x2 v = { pk(dB[0],  dB[1]),  pk(dB[2],  dB[3])  }; *(u32x2*)&vc[1][tr][cb] = v; }
        { u32x2 v = { pk(dQa[0], dQa[1]), pk(dQa[2], dQa[3]) }; *(u32x2*)&vc[2][tr][cb] = v; }
        { u32x2 v = { pk(dQb[0], dQb[1]), pk(dQb[2], dQb[3]) }; *(u32x2*)&vc[3][tr][cb] = v; }
    }
    __syncthreads();

    // ---- Stage H: horizontal conv via mfma(A=Toeplitz, B=vc) + SSIM map. ----
    // D[m][n] = sum_k w[k-m] * vc[row n][cb+k] = out[row n][col cb+m].
    // Lane(tr,g) reg i -> row tr, out col cb+4g+i.
    float local = 0.f;
    for (int t = wave; t < 32; t += 8) {
        const int cb = 16 * t;
        const f16x8 bA  = *(const f16x8*)&vc[0][tr][cb + k0];
        const f16x8 bB  = *(const f16x8*)&vc[1][tr][cb + k0];
        const f16x8 bQa = *(const f16x8*)&vc[2][tr][cb + k0];
        const f16x8 bQb = *(const f16x8*)&vc[3][tr][cb + k0];
        const f32x4 rA  = __builtin_amdgcn_mfma_f32_16x16x32_f16(tw, bA,  z4, 0, 0, 0);
        const f32x4 rB  = __builtin_amdgcn_mfma_f32_16x16x32_f16(tw, bB,  z4, 0, 0, 0);
        const f32x4 rQa = __builtin_amdgcn_mfma_f32_16x16x32_f16(tw, bQa, z4, 0, 0, 0);
        const f32x4 rQb = __builtin_amdgcn_mfma_f32_16x16x32_f16(tw, bQb, z4, 0, 0, 0);

        #pragma unroll
        for (int i = 0; i < 4; ++i) {
            const float A  = rA[i],  Bv = rB[i];
            const float Qa = rQa[i], Qb = rQb[i];
            const float u = A * A, v = Bv * Bv;
            const float t1 = u - v;                              // 4*mu1*mu2
            const float t2 = u + v;                              // 2*(mu1^2+mu2^2)
            const float num1 = fmaf(0.5f, t1, C1);
            const float den1 = fmaf(0.5f, t2, C1);
            const float num2 = fmaf(0.5f, (Qa - Qb) - t1, C2);   // 2*sigma12 + C2
            const float den2 = fmaf(0.5f, (Qa + Qb) - t2, C2);   // sig1+sig2 + C2
            local += (num1 * num2) * __builtin_amdgcn_rcpf(den1 * den2);
        }
    }

    #pragma unroll
    for (int off = 32; off > 0; off >>= 1) local += __shfl_down(local, off, 64);
    if (lane == 0) red[wave] = local;
    __syncthreads();
    if (tid == 0) {
        float s = 0.f;
        #pragma unroll
        for (int wv = 0; wv < 8; ++wv) s += red[wv];
        part[blockIdx.y * NBANDS + band] = s;
    }
}

__global__ __launch_bounds__(512)
void ssim_final(const float* __restrict__ part, float* __restrict__ out)
{
    __shared__ double red[8];
    const int tid = threadIdx.x;
    double s = 0.0;
    for (int i = tid; i < NB; i += 512) s += (double)part[i];
    #pragma unroll
    for (int off = 32; off > 0; off >>= 1) s += __shfl_down(s, off, 64);
    if ((tid & 63) == 0) red[tid >> 6] = s;
    __syncthreads();
    if (tid == 0) {
        double t = 0.0;
        #pragma unroll
        for (int wv = 0; wv < 8; ++wv) t += red[wv];
        out[0] = (float)(1.0 - t / NTOT);
    }
}

extern "C" void kernel_launch(void* const* d_in, const int* in_sizes, int n_in,
                              void* d_out, int out_size, void* d_ws, size_t ws_size,
                              hipStream_t stream)
{
    const float* img1 = (const float*)d_in[0];
    const float* img2 = (const float*)d_in[1];
    float* out = (float*)d_out;
    float* part = (float*)d_ws;   // NB floats, fully rewritten each call

    Wts wts;
    double wd[11], s = 0.0;
    for (int k = 0; k < 11; ++k) {
        const double d = (double)(k - 5);
        wd[k] = exp(-0.5 / (1.5 * 1.5) * d * d);
        s += wd[k];
    }
    for (int k = 0; k < 11; ++k) wts.w[k] = (float)(wd[k] / s);

    dim3 grid(NBANDS, NPLANES);
    ssim_main<<<grid, 512, 0, stream>>>(img1, img2, part, wts);
    ssim_final<<<1, 512, 0, stream>>>(part, out);
}